// Round 1
// baseline (4382.868 us; speedup 1.0000x reference)
//
#include <hip/hip_runtime.h>
#include <hip/hip_bf16.h>

typedef __attribute__((ext_vector_type(8))) short bh8;   // 8 x bf16 (4 VGPRs)
typedef __attribute__((ext_vector_type(4))) float f4;    // MFMA accumulator

static constexpr int T_STEPS = 128;
static constexpr int BTOT    = 2048;
static constexpr int HD      = 256;
static constexpr int NG      = 768;   // 3*H
static constexpr int LOUT    = 100;
static constexpr int LDS_STRIDE = 264; // 256 + 8 pad (bf16 elems) -> conflict-free ds_read_b128

__device__ __forceinline__ short f2bf(float f){
  unsigned u = __builtin_bit_cast(unsigned, f);
  unsigned r = (u + 0x7FFFu + ((u >> 16) & 1u)) >> 16;   // RNE
  return (short)(unsigned short)r;
}

__device__ __forceinline__ f4 mfma16(bh8 a, bh8 b, f4 c){
  return __builtin_amdgcn_mfma_f32_16x16x32_bf16(a, b, c, 0, 0, 0);
}

__device__ __forceinline__ float sigm(float x){
  return __builtin_amdgcn_rcpf(1.f + __expf(-x));
}
__device__ __forceinline__ float tanh_f(float x){
  // tanh(x) = 1 - 2/(exp(2x)+1); correct saturation at +-inf
  return 1.f - 2.f*__builtin_amdgcn_rcpf(1.f + __expf(2.f*x));
}

// ---------------- prep: E0 = emb @ w_ih0^T + b_ih0  ([64][768] f32) ----------------
__global__ void e0_kernel(const float* __restrict__ emb, const float* __restrict__ w_ih0,
                          const float* __restrict__ b_ih0, float* __restrict__ E0)
{
  int tid = blockIdx.x*blockDim.x + threadIdx.x;
  if (tid >= 64*NG) return;
  int v = tid / NG, n = tid % NG;
  const float4* er = (const float4*)(emb + (size_t)v*HD);
  const float4* wr = (const float4*)(w_ih0 + (size_t)n*HD);
  float s = 0.f;
#pragma unroll 4
  for (int k=0;k<HD/4;++k){
    float4 a = er[k], b = wr[k];
    s += a.x*b.x + a.y*b.y + a.z*b.z + a.w*b.w;
  }
  E0[tid] = s + b_ih0[n];
}

// ---------------- prep: pack all weights into B-fragment-linear bf16 tiles ----------------
// tile = 1KB = 64 lanes x 16B. Value at [tile][lane][e] = W[n][k] with
// n = tilecol*16 + (lane&15), k = kt*32 + (lane>>4)*8 + e.
// tiles 0..383    : layer0 w_hh0   [wave(8)][gate*2+nt(6)][kt(8)]
// tiles 384..1151 : layer1 [w_ih1 (kt<8) ; w_hh1 (kt>=8)] [wave][6][kt(16)]
// tiles 1152..1279: w1 [wave][nt(2)][kt(8)]
// tiles 1280..1335: w2 (pad N 100->112) [nt7(7)][kt(8)]
__global__ void pack_kernel(const float* __restrict__ w_hh0, const float* __restrict__ w_ih1,
                            const float* __restrict__ w_hh1, const float* __restrict__ w1,
                            const float* __restrict__ w2, short* __restrict__ pack)
{
  int tid = blockIdx.x*blockDim.x + threadIdx.x;
  if (tid >= 1336*64) return;
  int t = tid >> 6, lane = tid & 63;
  int l15 = lane & 15, lq = lane >> 4;
  const float* src = nullptr;
  bool zero = false;
  if (t < 384){
    int w = t/48, rem = t%48, i = rem/8, kt = rem%8;
    int n = (i>>1)*256 + w*32 + (i&1)*16 + l15;
    src = w_hh0 + (size_t)n*HD + kt*32 + lq*8;
  } else if (t < 1152){
    int tt = t - 384, w = tt/96, rem = tt%96, i = rem/16, kt = rem%16;
    int n = (i>>1)*256 + w*32 + (i&1)*16 + l15;
    src = (kt < 8) ? (w_ih1 + (size_t)n*HD + kt*32 + lq*8)
                   : (w_hh1 + (size_t)n*HD + (kt-8)*32 + lq*8);
  } else if (t < 1280){
    int tt = t - 1152, w = tt/16, rem = tt%16, ntt = rem/8, kt = rem%8;
    int n = w*32 + ntt*16 + l15;
    src = w1 + (size_t)n*HD + kt*32 + lq*8;
  } else {
    int tt = t - 1280, ntt = tt/8, kt = tt%8;
    int n = ntt*16 + l15;
    if (n < LOUT) src = w2 + (size_t)n*HD + kt*32 + lq*8;
    else zero = true;
  }
  bh8 o;
#pragma unroll
  for (int e=0;e<8;++e) o[e] = zero ? (short)0 : f2bf(src[e]);
  ((bh8*)pack)[tid] = o;
}

// ---------------- main: fused 2-layer GRU scan + head, 1 wg = 16 batch rows ----------------
__global__ __launch_bounds__(512, 2)
void rnn_main(const int* __restrict__ tokens, const int* __restrict__ lens,
              const float* __restrict__ E0, const short* __restrict__ pack,
              const float* __restrict__ b_hh0, const float* __restrict__ b_ih1,
              const float* __restrict__ b_hh1, const float* __restrict__ b1,
              const float* __restrict__ b2, float* __restrict__ out)
{
  const int tid  = threadIdx.x;
  const int wid  = tid >> 6;      // wave 0..7, owns hidden dims [32*wid, 32*wid+32)
  const int lane = tid & 63;
  const int l15  = lane & 15;
  const int lq   = lane >> 4;
  const int b0   = blockIdx.x * 16;

  __shared__ __align__(16) short s0_lds[16*LDS_STRIDE]; // layer0 state (bf16, A-readable)
  __shared__ __align__(16) short s1_lds[16*LDS_STRIDE]; // layer1 state
  __shared__ float bias0[NG], biasI1[NG], biasH1[NG], b1s[HD], b2s[112];

  for (int i = tid; i < 16*LDS_STRIDE; i += 512){ s0_lds[i] = 0; s1_lds[i] = 0; }
  for (int i = tid; i < NG; i += 512){ bias0[i] = b_hh0[i]; biasI1[i] = b_ih1[i]; biasH1[i] = b_hh1[i]; }
  if (tid < HD)  b1s[tid] = b1[tid];
  if (tid < 112) b2s[tid] = (tid < LOUT) ? b2[tid] : 0.f;

  int mylens[4];
#pragma unroll
  for (int r=0;r<4;++r) mylens[r] = lens[b0 + lq*4 + r];

  float h0s[2][4], h1s[2][4], outf[2][4];
#pragma unroll
  for (int nt=0;nt<2;++nt)
#pragma unroll
    for (int r=0;r<4;++r){ h0s[nt][r]=0.f; h1s[nt][r]=0.f; outf[nt][r]=0.f; }

  const bh8* __restrict__ packL0 = (const bh8*)pack + (size_t)(       wid*48)*64 + lane;
  const bh8* __restrict__ packL1 = (const bh8*)pack + (size_t)( 384 + wid*96)*64 + lane;
  const bh8* __restrict__ packW1 = (const bh8*)pack + (size_t)(1152 + wid*16)*64 + lane;
  const bh8* __restrict__ packW2 = (const bh8*)pack + (size_t)(1280 + wid*8 )*64 + lane;

  const short* s0p = &s0_lds[l15*LDS_STRIDE + lq*8];  // A-frag base: row l15, k0 = lq*8
  const short* s1p = &s1_lds[l15*LDS_STRIDE + lq*8];

  const f4 zf = {0.f, 0.f, 0.f, 0.f};

  __syncthreads();

#pragma unroll 1
  for (int t = 0; t < T_STEPS; ++t){
    // token ids for this step's 4 rows (issued early; consumed in epilogue0)
    int tokr[4];
#pragma unroll
    for (int r=0;r<4;++r) tokr[r] = tokens[t*BTOT + b0 + lq*4 + r];

    // ---- layer 0 GEMM: gh0 = s0 @ w_hh0^T  (K=256) ----
    bh8 a1[16];
#pragma unroll
    for (int kt=0;kt<8;++kt) a1[kt] = *(const bh8*)(s0p + kt*32);
    f4 acc0[6];
#pragma unroll
    for (int i=0;i<6;++i) acc0[i] = zf;
#pragma unroll
    for (int i=0;i<6;++i){
#pragma unroll
      for (int kt=0;kt<8;++kt)
        acc0[i] = mfma16(a1[kt], packL0[(i*8+kt)*64], acc0[i]);
    }
    __syncthreads();  // A: all waves done reading s0_lds

    // ---- layer 0 epilogue: r,z,n + state update; gi0 via E0[token] gather ----
#pragma unroll
    for (int nt=0;nt<2;++nt){
      const int jb = wid*32 + nt*16 + l15;
      const float bhr = bias0[jb], bhz = bias0[256+jb], bhn = bias0[512+jb];
#pragma unroll
      for (int r4=0;r4<4;++r4){
        const int brow = lq*4 + r4;
        const float* e0p = E0 + (size_t)tokr[r4]*NG + jb;
        const float gir = e0p[0], giz = e0p[256], gin = e0p[512];
        const float rg = sigm(acc0[0+nt][r4] + bhr + gir);
        const float zg = sigm(acc0[2+nt][r4] + bhz + giz);
        const float ng = tanh_f(gin + rg*(acc0[4+nt][r4] + bhn));
        float h = h0s[nt][r4];
        h = ng + zg*(h - ng);                 // (1-z)*n + z*h
        h0s[nt][r4] = h;
        s0_lds[brow*LDS_STRIDE + jb] = f2bf(h);
      }
    }
    __syncthreads();  // B: s0_lds now holds s0_t

    // ---- layer 1 GEMM: A = [s0_t | s1_{t-1}], K=512, B = [w_ih1 ; w_hh1] ----
#pragma unroll
    for (int kt=0;kt<8;++kt) a1[kt]   = *(const bh8*)(s0p + kt*32);
#pragma unroll
    for (int kt=0;kt<8;++kt) a1[8+kt] = *(const bh8*)(s1p + kt*32);
    f4 accr[2], accz[2], accni[2], accnh[2];
#pragma unroll
    for (int nt=0;nt<2;++nt){ accr[nt]=zf; accz[nt]=zf; accni[nt]=zf; accnh[nt]=zf; }
#pragma unroll
    for (int nt=0;nt<2;++nt){
#pragma unroll
      for (int kt=0;kt<16;++kt)            // r gate: i_r + h_r fused
        accr[nt] = mfma16(a1[kt], packL1[((0+nt)*16+kt)*64], accr[nt]);
#pragma unroll
      for (int kt=0;kt<16;++kt)            // z gate fused
        accz[nt] = mfma16(a1[kt], packL1[((2+nt)*16+kt)*64], accz[nt]);
#pragma unroll
      for (int kt=0;kt<8;++kt)             // n gate: i_n separate
        accni[nt] = mfma16(a1[kt], packL1[((4+nt)*16+kt)*64], accni[nt]);
#pragma unroll
      for (int kt=8;kt<16;++kt)            // n gate: h_n separate (gets r*)
        accnh[nt] = mfma16(a1[kt], packL1[((4+nt)*16+kt)*64], accnh[nt]);
    }
    __syncthreads();  // C: all waves done reading s0_lds/s1_lds

    // ---- layer 1 epilogue + output capture at t == lens[b] ----
#pragma unroll
    for (int nt=0;nt<2;++nt){
      const int jb = wid*32 + nt*16 + l15;
      const float bir = biasI1[jb],     bhr = biasH1[jb];
      const float biz = biasI1[256+jb], bhz = biasH1[256+jb];
      const float bin = biasI1[512+jb], bhn = biasH1[512+jb];
#pragma unroll
      for (int r4=0;r4<4;++r4){
        const int brow = lq*4 + r4;
        const float rg = sigm(accr[nt][r4] + bir + bhr);
        const float zg = sigm(accz[nt][r4] + biz + bhz);
        const float ng = tanh_f((accni[nt][r4] + bin) + rg*(accnh[nt][r4] + bhn));
        float h = h1s[nt][r4];
        h = ng + zg*(h - ng);
        h1s[nt][r4] = h;
        if (mylens[r4] == t) outf[nt][r4] = h;
        s1_lds[brow*LDS_STRIDE + jb] = f2bf(h);
      }
    }
    // no barrier here: next iteration's barriers A/B order s1 writes vs reads
  }

  // ---- head: z = LeakyReLU(out_t @ w1^T + b1); enc = z @ w2^T + b2 ----
#pragma unroll
  for (int nt=0;nt<2;++nt){
    const int jb = wid*32 + nt*16 + l15;
#pragma unroll
    for (int r4=0;r4<4;++r4)
      s0_lds[(lq*4+r4)*LDS_STRIDE + jb] = f2bf(outf[nt][r4]);
  }
  __syncthreads();

  {
    bh8 ah[8];
#pragma unroll
    for (int kt=0;kt<8;++kt) ah[kt] = *(const bh8*)(s0p + kt*32);
    f4 az[2]; az[0]=zf; az[1]=zf;
#pragma unroll
    for (int nt=0;nt<2;++nt)
#pragma unroll
      for (int kt=0;kt<8;++kt)
        az[nt] = mfma16(ah[kt], packW1[(nt*8+kt)*64], az[nt]);
#pragma unroll
    for (int nt=0;nt<2;++nt){
      const int jb = wid*32 + nt*16 + l15;
#pragma unroll
      for (int r4=0;r4<4;++r4){
        float v = az[nt][r4] + b1s[jb];
        v = (v >= 0.f) ? v : 0.01f*v;     // LeakyReLU
        s1_lds[(lq*4+r4)*LDS_STRIDE + jb] = f2bf(v);
      }
    }
  }
  __syncthreads();

  if (wid < 7){
    bh8 a2[8];
#pragma unroll
    for (int kt=0;kt<8;++kt) a2[kt] = *(const bh8*)(s1p + kt*32);
    f4 acc2 = zf;
#pragma unroll
    for (int kt=0;kt<8;++kt)
      acc2 = mfma16(a2[kt], packW2[kt*64], acc2);
    const int n2 = wid*16 + l15;
    if (n2 < LOUT){
#pragma unroll
      for (int r4=0;r4<4;++r4)
        out[(size_t)(b0 + lq*4 + r4)*LOUT + n2] = acc2[r4] + b2s[n2];
    }
  }
}

extern "C" void kernel_launch(void* const* d_in, const int* in_sizes, int n_in,
                              void* d_out, int out_size, void* d_ws, size_t ws_size,
                              hipStream_t stream)
{
  const int*   tokens = (const int*)  d_in[0];
  const int*   lens   = (const int*)  d_in[1];
  const float* emb    = (const float*)d_in[2];
  const float* w_ih0  = (const float*)d_in[3];
  const float* w_hh0  = (const float*)d_in[4];
  const float* b_ih0  = (const float*)d_in[5];
  const float* b_hh0  = (const float*)d_in[6];
  const float* w_ih1  = (const float*)d_in[7];
  const float* w_hh1  = (const float*)d_in[8];
  const float* b_ih1  = (const float*)d_in[9];
  const float* b_hh1  = (const float*)d_in[10];
  const float* w1     = (const float*)d_in[11];
  const float* b1     = (const float*)d_in[12];
  const float* w2     = (const float*)d_in[13];
  const float* b2     = (const float*)d_in[14];

  float* E0   = (float*)d_ws;                                  // 64*768*4 = 196608 B
  short* pack = (short*)((char*)d_ws + 64*NG*sizeof(float));   // 1336 KiB packed bf16 tiles

  e0_kernel  <<<(64*NG + 255)/256,   256, 0, stream>>>(emb, w_ih0, b_ih0, E0);
  pack_kernel<<<(1336*64 + 255)/256, 256, 0, stream>>>(w_hh0, w_ih1, w_hh1, w1, w2, pack);
  rnn_main   <<<128, 512, 0, stream>>>(tokens, lens, E0, pack,
                                       b_hh0, b_ih1, b_hh1, b1, b2, (float*)d_out);
}